// Round 6
// baseline (57.263 us; speedup 1.0000x reference)
//
#include <hip/hip_runtime.h>
#include <hip/hip_bf16.h>

// Problem constants (from setup_inputs): N=8192 points, k=8.
#define NPTS 8192
#define KNN 8
#define SEGS 32                // candidate segments per point
#define PPB 16                 // points per block
#define BLK (SEGS * PPB)       // 512 threads, 8 waves
#define SEGLEN (NPTS / SEGS)   // 256 candidates per segment
#define NSAMP 16               // threshold samples per thread (512 per point)
#define NWORDS (SEGLEN / 32)   // 8 bitmask words per thread

// Pack (x,y,z,|p|^2) and zero the output accumulator.
__global__ __launch_bounds__(256) void prep_kernel(const float* __restrict__ means,
                                                   float4* __restrict__ pts,
                                                   float* __restrict__ out) {
    int i = blockIdx.x * 256 + threadIdx.x;
    if (i == 0 && blockIdx.x == 0) out[0] = 0.0f;
    if (i < NPTS) {
        float x = means[3 * i + 0];
        float y = means[3 * i + 1];
        float z = means[3 * i + 2];
        pts[i] = make_float4(x, y, z, x * x + y * y + z * z);
    }
}

// Exact kNN via sample-threshold filter with REGISTER-BITMASK survivors:
//  A) 512 sampled candidates/point -> T = 8th-smallest sampled key (upper bound
//     on the true 8th key, since the sample is a subset).
//  B) full scan; keep-bit per candidate into 8 u32 register words.
//     keep = d2_bits <= (T | 0x1FFF)  ===  (d2_bits & ~0x1FFF) <= T_masked,
//     so the survivor set is exactly the old {key <= T} superset of the top-8.
//     2 VALU/cand for recording, no LDS traffic, no capacity limit.
//  C) decode set bits (~4/thread), recompute exact f32 d2, insert-8 + tree merge.
// Keys pack (d2 top 19 bits | 13-bit idx): unique, total order, jax tie-break.
__global__ __launch_bounds__(BLK) void knn_kernel(const float4* __restrict__ pts,
                                                  const float* __restrict__ normals,
                                                  float* __restrict__ out) {
    __shared__ unsigned int lds_keys[SEGS][PPB][KNN + 1];  // merge scratch (+1 pad)
    __shared__ unsigned int lds_T[PPB];
    __shared__ int lds_nbr[PPB][KNN];
    __shared__ float lds_red[BLK / 64];

    const int tid = threadIdx.x;
    const int pl = tid & (PPB - 1);   // point within block
    const int seg = tid >> 4;         // segment (PPB==16)
    const int i = blockIdx.x * PPB + pl;

    const float4 mp = pts[i];
    const float mx2 = -2.0f * mp.x;
    const float my2 = -2.0f * mp.y;
    const float mz2 = -2.0f * mp.z;
    const int j0 = seg * SEGLEN;

    unsigned int best[KNN];
#pragma unroll
    for (int s = 0; s < KNN; ++s) best[s] = 0xFFFFFFFFu;

    // ---- Phase A: sampled scan with full insert (16 samples, stride 16) ----
#pragma unroll
    for (int s8 = 0; s8 < NSAMP; ++s8) {
        const int j = j0 + s8 * (SEGLEN / NSAMP);
        const float4 q = pts[j];
        const float d2 = fmaxf(fmaf(mx2, q.x, fmaf(my2, q.y, fmaf(mz2, q.z, mp.w + q.w))), 0.0f);
        unsigned int key = (__float_as_uint(d2) & 0xFFFFE000u) | (unsigned int)j;
        key = (j == i) ? 0xFFFFFFFFu : key;  // exclude self
#pragma unroll
        for (int s = 0; s < KNN; ++s) {
            const unsigned int lo = min(best[s], key);
            const unsigned int hi = max(best[s], key);
            best[s] = lo;
            key = hi;
        }
    }

#pragma unroll
    for (int s = 0; s < KNN; ++s) lds_keys[seg][pl][s] = best[s];
    for (int st = 1; st < SEGS; st <<= 1) {
        __syncthreads();
        if ((seg & (2 * st - 1)) == 0) {
#pragma unroll
            for (int s = 0; s < KNN; ++s) {
                unsigned int key = lds_keys[seg + st][pl][s];
#pragma unroll
                for (int t = 0; t < KNN; ++t) {
                    const unsigned int lo = min(best[t], key);
                    const unsigned int hi = max(best[t], key);
                    best[t] = lo;
                    key = hi;
                }
            }
#pragma unroll
            for (int s = 0; s < KNN; ++s) lds_keys[seg][pl][s] = best[s];
        }
    }
    if (seg == 0) lds_T[pl] = best[7];  // 8th-smallest of 512 samples
    __syncthreads();
    // round idx bits up so a plain u32 compare on d2_bits equals the masked-key test
    const unsigned int Tp = lds_T[pl] | 0x1FFFu;

    // ---- Phase B: full scan, survivors -> register bitmask (2 ops/cand) ----
    unsigned int bits[NWORDS];
    for (int w = 0; w < NWORDS; ++w) {
        const float4* __restrict__ pw = pts + j0 + w * 32;
        unsigned int m = 0;
#pragma unroll
        for (int c = 0; c < 32; ++c) {
            const float4 q = pw[c];
            const float d2 = fmaxf(fmaf(mx2, q.x, fmaf(my2, q.y, fmaf(mz2, q.z, mp.w + q.w))), 0.0f);
            const bool keep = __float_as_uint(d2) <= Tp;
            m |= keep ? (1u << c) : 0u;
        }
        bits[w] = m;
    }

    // ---- Phase C: decode survivors, exact key, top-8 insert ----
#pragma unroll
    for (int s = 0; s < KNN; ++s) best[s] = 0xFFFFFFFFu;
    for (int w = 0; w < NWORDS; ++w) {
        unsigned int m = bits[w];
        while (m) {
            const int c = __ffs(m) - 1;
            m &= m - 1;  // clear lowest set bit
            const int j = j0 + w * 32 + c;
            const float4 q = pts[j];
            const float d2 = fmaxf(fmaf(mx2, q.x, fmaf(my2, q.y, fmaf(mz2, q.z, mp.w + q.w))), 0.0f);
            unsigned int key = (__float_as_uint(d2) & 0xFFFFE000u) | (unsigned int)j;
            key = (j == i) ? 0xFFFFFFFFu : key;  // drop self
#pragma unroll
            for (int t = 0; t < KNN; ++t) {
                const unsigned int lo = min(best[t], key);
                const unsigned int hi = max(best[t], key);
                best[t] = lo;
                key = hi;
            }
        }
    }

#pragma unroll
    for (int s = 0; s < KNN; ++s) lds_keys[seg][pl][s] = best[s];
    for (int st = 1; st < SEGS; st <<= 1) {
        __syncthreads();
        if ((seg & (2 * st - 1)) == 0) {
#pragma unroll
            for (int s = 0; s < KNN; ++s) {
                unsigned int key = lds_keys[seg + st][pl][s];
#pragma unroll
                for (int t = 0; t < KNN; ++t) {
                    const unsigned int lo = min(best[t], key);
                    const unsigned int hi = max(best[t], key);
                    best[t] = lo;
                    key = hi;
                }
            }
#pragma unroll
            for (int s = 0; s < KNN; ++s) lds_keys[seg][pl][s] = best[s];
        }
    }
    __syncthreads();
    if (seg == 0) {
#pragma unroll
        for (int s = 0; s < KNN; ++s) lds_nbr[pl][s] = (int)(best[s] & 0x1FFFu);
    }
    __syncthreads();

    // plane distance: one thread per (point, neighbor-rank) for segs 0..7
    float pd = 0.0f;
    if (seg < KNN) {
        const int nbr = lds_nbr[pl][seg];
        const float4 q = pts[nbr];
        const float nx = normals[3 * i + 0];
        const float ny = normals[3 * i + 1];
        const float nz = normals[3 * i + 2];
        pd = fabsf((q.x - mp.x) * nx + (q.y - mp.y) * ny + (q.z - mp.z) * nz);
    }

    // block reduction
    float v = pd;
#pragma unroll
    for (int off = 32; off > 0; off >>= 1) v += __shfl_down(v, off);
    const int wid = tid >> 6;
    if ((tid & 63) == 0) lds_red[wid] = v;
    __syncthreads();
    if (tid == 0) {
        float s = 0.0f;
#pragma unroll
        for (int w = 0; w < BLK / 64; ++w) s += lds_red[w];
        atomicAdd(out, s * (1.0f / ((float)NPTS * (float)KNN)));
    }
}

extern "C" void kernel_launch(void* const* d_in, const int* in_sizes, int n_in,
                              void* d_out, int out_size, void* d_ws, size_t ws_size,
                              hipStream_t stream) {
    const float* means = (const float*)d_in[0];
    const float* normals = (const float*)d_in[1];
    float* out = (float*)d_out;
    float4* pts = (float4*)d_ws;  // 8192 * 16B = 128 KB scratch

    prep_kernel<<<(NPTS + 255) / 256, 256, 0, stream>>>(means, pts, out);
    knn_kernel<<<NPTS / PPB, BLK, 0, stream>>>(pts, normals, out);
}